// Round 1
// baseline (225.554 us; speedup 1.0000x reference)
//
#include <hip/hip_runtime.h>
#include <hip/hip_bf16.h>
#include <stdint.h>

// Problem constants (fixed by setup_inputs): Xp(16384,3) X(8192,3) W(64,8192) eps scalar
#define M_ROWS 16384
#define N_PTS  8192
#define K_OUT  64
#define NSPLIT 4   // N-dimension split for occupancy (1024 blocks -> ~4 blocks/CU)

typedef short bf16x8 __attribute__((ext_vector_type(8)));  // 8 bf16 = 4 VGPRs (MFMA A/B frag)
typedef float f32x4  __attribute__((ext_vector_type(4)));  // MFMA C/D frag

union ABFrag { bf16x8 v; uint32_t u[4]; };

// pack two f32 -> two bf16 (round-half-up: +0x8000 then take hi16) in ONE v_perm_b32
__device__ __forceinline__ uint32_t pack_bf16_rhu(float a, float b) {
    uint32_t ua = __builtin_bit_cast(uint32_t, a) + 0x8000u;
    uint32_t ub = __builtin_bit_cast(uint32_t, b) + 0x8000u;
    // dst bytes [0,1] = ua bytes [2,3]; dst bytes [2,3] = ub bytes [2,3]
    return __builtin_amdgcn_perm(ub, ua, 0x07060302u);
}

// RNE pack (used only in prep for W — off the critical path)
__device__ __forceinline__ uint32_t pack_bf16_rne(float a, float b) {
    uint32_t ua = __builtin_bit_cast(uint32_t, a);
    ua += 0x7FFFu + ((ua >> 16) & 1u);
    uint32_t ub = __builtin_bit_cast(uint32_t, b);
    ub += 0x7FFFu + ((ub >> 16) & 1u);
    return __builtin_amdgcn_perm(ub, ua, 0x07060302u);
}

// ---------------- prep: W->bf16 (RNE), X->eps-scaled SoA, zero d_out ----------------
// grid 1568 blocks x 256:
//   [0,512):    convert W   (524288 floats, 4/thread)
//   [512,1536): zero d_out  (1048576 floats, 4/thread)
//   [1536,1568): X SoA      (8192 points, 1/thread)
__global__ __launch_bounds__(256) void rbf_prep(
    const float* __restrict__ Wf, const float* __restrict__ X,
    const float* __restrict__ epsp, float* __restrict__ out,
    short* __restrict__ Wb, float* __restrict__ Xx,
    float* __restrict__ Xy, float* __restrict__ Xz)
{
    const int bid = blockIdx.x, tid = threadIdx.x;
    if (bid < 512) {
        const int i = bid * 256 + tid;             // 131072 float4s
        const float4 w = ((const float4*)Wf)[i];
        uint2 p;
        p.x = pack_bf16_rne(w.x, w.y);
        p.y = pack_bf16_rne(w.z, w.w);
        ((uint2*)Wb)[i] = p;
    } else if (bid < 1536) {
        const int i = (bid - 512) * 256 + tid;     // 262144 float4s = 1,048,576 floats
        const float4 zz = make_float4(0.f, 0.f, 0.f, 0.f);
        ((float4*)out)[i] = zz;
    } else {
        const int n = (bid - 1536) * 256 + tid;    // 8192 points
        const float e = *epsp;
        Xx[n] = X[3 * n + 0] * e;
        Xy[n] = X[3 * n + 1] * e;
        Xz[n] = X[3 * n + 2] * e;
    }
}

// ---------------- main: fused phi + MFMA GEMM ----------------
// wave = 16 rows x 64 cols, N step 32 via v_mfma_f32_16x16x32_bf16.
// A frag: A[m=lane&15][k=(lane>>4)*8+j]  -> lane computes 8 phis for one row, 8 consecutive n
// B frag: B[k=(lane>>4)*8+j][n=lane&15]  -> Wb[kt*16+(lane&15)][n0+(lane>>4)*8+j]
// C/D   : col=lane&15, row=(lane>>4)*4+reg   (verified m89/m91)
__global__ __launch_bounds__(256, 4) void rbf_main(
    const float* __restrict__ Xp, const short* __restrict__ Wb,
    const float* __restrict__ Xx, const float* __restrict__ Xy,
    const float* __restrict__ Xz, const float* __restrict__ epsp,
    float* __restrict__ out)
{
    const int tid  = threadIdx.x;
    const int lane = tid & 63;
    const int wv   = tid >> 6;
    const int l15  = lane & 15;
    const int g    = lane >> 4;

    const int bid = blockIdx.x;
    const int ns  = bid & (NSPLIT - 1);
    const int rg  = bid >> 2;                 // log2(NSPLIT)
    const int rowbase = rg * 64 + wv * 16;
    const int nbase   = ns * (N_PTS / NSPLIT);

    // this lane's Xp row, pre-scaled by eps (phi = sqrt(d2(eps*Xp, eps*X) + 1))
    const float eps = *epsp;
    const int r = rowbase + l15;
    const float px = Xp[r * 3 + 0] * eps;
    const float py = Xp[r * 3 + 1] * eps;
    const float pz = Xp[r * 3 + 2] * eps;

    f32x4 acc0 = {0.f, 0.f, 0.f, 0.f};
    f32x4 acc1 = acc0, acc2 = acc0, acc3 = acc0;

    const short* wb0 = Wb + (0 * 16 + l15) * N_PTS;
    const short* wb1 = Wb + (1 * 16 + l15) * N_PTS;
    const short* wb2 = Wb + (2 * 16 + l15) * N_PTS;
    const short* wb3 = Wb + (3 * 16 + l15) * N_PTS;

    #pragma unroll 2
    for (int s = 0; s < N_PTS / NSPLIT; s += 32) {
        const int ng = nbase + s + g * 8;

        const float4 x0 = *(const float4*)(Xx + ng);
        const float4 x1 = *(const float4*)(Xx + ng + 4);
        const float4 y0 = *(const float4*)(Xy + ng);
        const float4 y1 = *(const float4*)(Xy + ng + 4);
        const float4 z0 = *(const float4*)(Xz + ng);
        const float4 z1 = *(const float4*)(Xz + ng + 4);

        const float xs[8] = {x0.x, x0.y, x0.z, x0.w, x1.x, x1.y, x1.z, x1.w};
        const float ys[8] = {y0.x, y0.y, y0.z, y0.w, y1.x, y1.y, y1.z, y1.w};
        const float zs[8] = {z0.x, z0.y, z0.z, z0.w, z1.x, z1.y, z1.z, z1.w};

        float t[8];
        #pragma unroll
        for (int j = 0; j < 8; ++j) {
            const float dx = px - xs[j];
            const float dy = py - ys[j];
            const float dz = pz - zs[j];
            float d = fmaf(dx, dx, 1.0f);
            d = fmaf(dy, dy, d);
            d = fmaf(dz, dz, d);
            t[j] = __builtin_amdgcn_sqrtf(d);   // raw v_sqrt_f32, no fixup
        }

        ABFrag a;
        #pragma unroll
        for (int j = 0; j < 4; ++j) a.u[j] = pack_bf16_rhu(t[2 * j], t[2 * j + 1]);

        const bf16x8 b0 = *(const bf16x8*)(wb0 + ng);
        const bf16x8 b1 = *(const bf16x8*)(wb1 + ng);
        const bf16x8 b2 = *(const bf16x8*)(wb2 + ng);
        const bf16x8 b3 = *(const bf16x8*)(wb3 + ng);

        acc0 = __builtin_amdgcn_mfma_f32_16x16x32_bf16(a.v, b0, acc0, 0, 0, 0);
        acc1 = __builtin_amdgcn_mfma_f32_16x16x32_bf16(a.v, b1, acc1, 0, 0, 0);
        acc2 = __builtin_amdgcn_mfma_f32_16x16x32_bf16(a.v, b2, acc2, 0, 0, 0);
        acc3 = __builtin_amdgcn_mfma_f32_16x16x32_bf16(a.v, b3, acc3, 0, 0, 0);
    }

    // C/D: row = rowbase + g*4 + reg, col = kt*16 + l15. NSPLIT partials -> atomicAdd.
    float* o = out + (rowbase + g * 4) * K_OUT + l15;
    #pragma unroll
    for (int reg = 0; reg < 4; ++reg) {
        atomicAdd(o + reg * K_OUT +  0, acc0[reg]);
        atomicAdd(o + reg * K_OUT + 16, acc1[reg]);
        atomicAdd(o + reg * K_OUT + 32, acc2[reg]);
        atomicAdd(o + reg * K_OUT + 48, acc3[reg]);
    }
}

extern "C" void kernel_launch(void* const* d_in, const int* in_sizes, int n_in,
                              void* d_out, int out_size, void* d_ws, size_t ws_size,
                              hipStream_t stream) {
    (void)in_sizes; (void)n_in; (void)out_size; (void)ws_size;
    const float* Xp  = (const float*)d_in[0];   // (16384,3)
    const float* X   = (const float*)d_in[1];   // (8192,3)
    const float* Wf  = (const float*)d_in[2];   // (64,8192)
    const float* eps = (const float*)d_in[3];   // scalar
    float* out = (float*)d_out;                 // (16384,64)

    // workspace layout: Wb bf16 1 MiB | Xx 32 KiB | Xy 32 KiB | Xz 32 KiB
    short* Wb = (short*)d_ws;
    float* Xx = (float*)((char*)d_ws + (1u << 20));
    float* Xy = Xx + N_PTS;
    float* Xz = Xy + N_PTS;

    rbf_prep<<<dim3(1568), dim3(256), 0, stream>>>(Wf, X, eps, out, Wb, Xx, Xy, Xz);
    rbf_main<<<dim3(M_ROWS / 64 * NSPLIT), dim3(256), 0, stream>>>(Xp, Wb, Xx, Xy, Xz, eps, out);
}

// Round 2
// 111.259 us; speedup vs baseline: 2.0273x; 2.0273x over previous
//
#include <hip/hip_runtime.h>
#include <hip/hip_bf16.h>
#include <stdint.h>

// Problem constants: Xp(16384,3) X(8192,3) W(64,8192) eps scalar -> out(16384,64)
#define M_ROWS 16384
#define N_PTS  8192
#define K_OUT  64
#define NSPLIT 8
#define SLICE  (N_PTS / NSPLIT)   // 1024 points per block

typedef short bf16x8 __attribute__((ext_vector_type(8)));
typedef float f32x4  __attribute__((ext_vector_type(4)));

union ABFrag { bf16x8 v; uint32_t u[4]; };
union BFrag  { uint4 q; bf16x8 v; };

// pack two f32 -> two bf16 (round-half-up) in one v_perm_b32
__device__ __forceinline__ uint32_t pack_bf16_rhu(float a, float b) {
    uint32_t ua = __builtin_bit_cast(uint32_t, a) + 0x8000u;
    uint32_t ub = __builtin_bit_cast(uint32_t, b) + 0x8000u;
    return __builtin_amdgcn_perm(ub, ua, 0x07060302u);
}
// RNE pack (prep only)
__device__ __forceinline__ uint32_t pack_bf16_rne(float a, float b) {
    uint32_t ua = __builtin_bit_cast(uint32_t, a);
    ua += 0x7FFFu + ((ua >> 16) & 1u);
    uint32_t ub = __builtin_bit_cast(uint32_t, b);
    ub += 0x7FFFu + ((ub >> 16) & 1u);
    return __builtin_amdgcn_perm(ub, ua, 0x07060302u);
}

// ---------------- prep ----------------
// blocks [0,256):  W -> fragment-linear bf16 Wt. Block b = n-step (32 pts).
//                  Wt uint4 index: (b*4 + kt)*64 + lane  holds
//                  W[kt*16 + (lane&15)][b*32 + (lane>>4)*8 + j], j=0..7 (RNE bf16)
// blocks [256,512): zero d_out (1,048,576 floats; 4 x float4 per thread)
// blocks [512,520): X -> eps-scaled SoA (4 points/thread)
__global__ __launch_bounds__(256) void rbf_prep(
    const float* __restrict__ Wf, const float* __restrict__ X,
    const float* __restrict__ epsp, float* __restrict__ out,
    uint4* __restrict__ Wt, float* __restrict__ Xx,
    float* __restrict__ Xy, float* __restrict__ Xz)
{
    const int bid = blockIdx.x, tid = threadIdx.x;
    if (bid < 256) {
        const int kt = tid >> 6, lane = tid & 63;
        const int l15 = lane & 15, g = lane >> 4;
        const int row = kt * 16 + l15;
        const int col = bid * 32 + g * 8;
        const float4* src = (const float4*)(Wf + row * N_PTS + col);
        const float4 w0 = src[0], w1 = src[1];
        uint4 p;
        p.x = pack_bf16_rne(w0.x, w0.y);
        p.y = pack_bf16_rne(w0.z, w0.w);
        p.z = pack_bf16_rne(w1.x, w1.y);
        p.w = pack_bf16_rne(w1.z, w1.w);
        Wt[(bid * 4 + kt) * 64 + lane] = p;
    } else if (bid < 512) {
        const int i = ((bid - 256) * 256 + tid) * 4;   // float4 index
        const float4 z = make_float4(0.f, 0.f, 0.f, 0.f);
        float4* o = (float4*)out + i;
        o[0] = z; o[1] = z; o[2] = z; o[3] = z;
    } else {
        const int n = ((bid - 512) * 256 + tid) * 4;   // 4 points
        const float e = *epsp;
        const float4* p = (const float4*)(X + 3 * n);
        const float4 p0 = p[0], p1 = p[1], p2 = p[2];
        *(float4*)(Xx + n) = make_float4(p0.x * e, p0.w * e, p1.z * e, p2.y * e);
        *(float4*)(Xy + n) = make_float4(p0.y * e, p1.x * e, p1.w * e, p2.z * e);
        *(float4*)(Xz + n) = make_float4(p0.z * e, p1.y * e, p2.x * e, p2.w * e);
    }
}

// ---------------- main: fused phi + MFMA ----------------
// 1024 blocks = 128 row-groups x 8 n-slices. Block: 4 waves x 2 row-tiles x 16 rows
// = 128 rows, slice of 1024 points. Coords in LDS (broadcast reads). W loads are
// fragment-linear: base + lane*16 B, fully coalesced, kt at +1024 B imm offsets.
__global__ __launch_bounds__(256, 4) void rbf_main(
    const float* __restrict__ Xp, const uint4* __restrict__ Wt,
    const float* __restrict__ Xx, const float* __restrict__ Xy,
    const float* __restrict__ Xz, const float* __restrict__ epsp,
    float* __restrict__ out)
{
    __shared__ float sX[SLICE], sY[SLICE], sZ[SLICE];

    const int tid  = threadIdx.x;
    const int lane = tid & 63;
    const int wv   = tid >> 6;
    const int l15  = lane & 15;
    const int g    = lane >> 4;

    const int bid  = blockIdx.x;
    const int ns   = bid & (NSPLIT - 1);
    const int rg   = bid >> 3;
    const int nbase = ns * SLICE;

    // stage eps-scaled coords into LDS (each thread: 3 x float4)
    {
        const int i = tid * 4;
        *(float4*)(sX + i) = *(const float4*)(Xx + nbase + i);
        *(float4*)(sY + i) = *(const float4*)(Xy + nbase + i);
        *(float4*)(sZ + i) = *(const float4*)(Xz + nbase + i);
    }

    const float eps = *epsp;
    const int rowbase = rg * 128 + wv * 16;
    const int r0 = rowbase + l15;
    const int r1 = r0 + 64;
    const float px0 = Xp[r0 * 3 + 0] * eps, py0 = Xp[r0 * 3 + 1] * eps, pz0 = Xp[r0 * 3 + 2] * eps;
    const float px1 = Xp[r1 * 3 + 0] * eps, py1 = Xp[r1 * 3 + 1] * eps, pz1 = Xp[r1 * 3 + 2] * eps;

    __syncthreads();

    f32x4 acc00 = {0.f,0.f,0.f,0.f}, acc01 = acc00, acc02 = acc00, acc03 = acc00;
    f32x4 acc10 = acc00, acc11 = acc00, acc12 = acc00, acc13 = acc00;

    // uint4 units: step stride 256, kt stride 64, + lane
    const uint4* wbase = Wt + (ns * 32) * 256 + lane;

    for (int s = 0; s < SLICE / 32; ++s) {
        const uint4* wp = wbase + s * 256;
        BFrag b0, b1, b2, b3;
        b0.q = wp[0];
        b1.q = wp[64];
        b2.q = wp[128];
        b3.q = wp[192];

        const int ci = s * 32 + g * 8;
        const float4 x0 = *(const float4*)(sX + ci), x1 = *(const float4*)(sX + ci + 4);
        const float4 y0 = *(const float4*)(sY + ci), y1 = *(const float4*)(sY + ci + 4);
        const float4 z0 = *(const float4*)(sZ + ci), z1 = *(const float4*)(sZ + ci + 4);

        const float xs[8] = {x0.x, x0.y, x0.z, x0.w, x1.x, x1.y, x1.z, x1.w};
        const float ys[8] = {y0.x, y0.y, y0.z, y0.w, y1.x, y1.y, y1.z, y1.w};
        const float zs[8] = {z0.x, z0.y, z0.z, z0.w, z1.x, z1.y, z1.z, z1.w};

        float t0[8], t1[8];
        #pragma unroll
        for (int j = 0; j < 8; ++j) {
            float dx = px0 - xs[j], dy = py0 - ys[j], dz = pz0 - zs[j];
            float d = fmaf(dx, dx, 1.0f); d = fmaf(dy, dy, d); d = fmaf(dz, dz, d);
            t0[j] = __builtin_amdgcn_sqrtf(d);
            dx = px1 - xs[j]; dy = py1 - ys[j]; dz = pz1 - zs[j];
            d = fmaf(dx, dx, 1.0f); d = fmaf(dy, dy, d); d = fmaf(dz, dz, d);
            t1[j] = __builtin_amdgcn_sqrtf(d);
        }

        ABFrag a0, a1;
        #pragma unroll
        for (int j = 0; j < 4; ++j) {
            a0.u[j] = pack_bf16_rhu(t0[2 * j], t0[2 * j + 1]);
            a1.u[j] = pack_bf16_rhu(t1[2 * j], t1[2 * j + 1]);
        }

        acc00 = __builtin_amdgcn_mfma_f32_16x16x32_bf16(a0.v, b0.v, acc00, 0, 0, 0);
        acc01 = __builtin_amdgcn_mfma_f32_16x16x32_bf16(a0.v, b1.v, acc01, 0, 0, 0);
        acc02 = __builtin_amdgcn_mfma_f32_16x16x32_bf16(a0.v, b2.v, acc02, 0, 0, 0);
        acc03 = __builtin_amdgcn_mfma_f32_16x16x32_bf16(a0.v, b3.v, acc03, 0, 0, 0);
        acc10 = __builtin_amdgcn_mfma_f32_16x16x32_bf16(a1.v, b0.v, acc10, 0, 0, 0);
        acc11 = __builtin_amdgcn_mfma_f32_16x16x32_bf16(a1.v, b1.v, acc11, 0, 0, 0);
        acc12 = __builtin_amdgcn_mfma_f32_16x16x32_bf16(a1.v, b2.v, acc12, 0, 0, 0);
        acc13 = __builtin_amdgcn_mfma_f32_16x16x32_bf16(a1.v, b3.v, acc13, 0, 0, 0);
    }

    // C/D: col = l15 (+16*kt), row = rowbase (+64*tile) + g*4 + reg. 8 partials -> atomicAdd.
    float* o0 = out + (rowbase + g * 4) * K_OUT + l15;
    float* o1 = o0 + 64 * K_OUT;
    #pragma unroll
    for (int reg = 0; reg < 4; ++reg) {
        atomicAdd(o0 + reg * K_OUT +  0, acc00[reg]);
        atomicAdd(o0 + reg * K_OUT + 16, acc01[reg]);
        atomicAdd(o0 + reg * K_OUT + 32, acc02[reg]);
        atomicAdd(o0 + reg * K_OUT + 48, acc03[reg]);
        atomicAdd(o1 + reg * K_OUT +  0, acc10[reg]);
        atomicAdd(o1 + reg * K_OUT + 16, acc11[reg]);
        atomicAdd(o1 + reg * K_OUT + 32, acc12[reg]);
        atomicAdd(o1 + reg * K_OUT + 48, acc13[reg]);
    }
}

extern "C" void kernel_launch(void* const* d_in, const int* in_sizes, int n_in,
                              void* d_out, int out_size, void* d_ws, size_t ws_size,
                              hipStream_t stream) {
    (void)in_sizes; (void)n_in; (void)out_size; (void)ws_size;
    const float* Xp  = (const float*)d_in[0];   // (16384,3)
    const float* X   = (const float*)d_in[1];   // (8192,3)
    const float* Wf  = (const float*)d_in[2];   // (64,8192)
    const float* eps = (const float*)d_in[3];   // scalar
    float* out = (float*)d_out;                 // (16384,64)

    // ws: Wt (fragment-linear bf16 W) 1 MiB | Xx 32 KiB | Xy 32 KiB | Xz 32 KiB
    uint4* Wt = (uint4*)d_ws;
    float* Xx = (float*)((char*)d_ws + (1u << 20));
    float* Xy = Xx + N_PTS;
    float* Xz = Xy + N_PTS;

    rbf_prep<<<dim3(520), dim3(256), 0, stream>>>(Wf, X, eps, out, Wt, Xx, Xy, Xz);
    rbf_main<<<dim3((M_ROWS / 128) * NSPLIT), dim3(256), 0, stream>>>(Xp, Wt, Xx, Xy, Xz, eps, out);
}